// Round 18
// baseline (148.165 us; speedup 1.0000x reference)
//
#include <hip/hip_runtime.h>
#include <hip/hip_bf16.h>
#include <math.h>

constexpr int NV = 32000;
constexpr int NE = 256;
constexpr int NH = 512;
constexpr int NB = 128;
constexpr int NS = 512;
constexpr int NX = NH + NE;   // 768, LSTM0 input dim
constexpr int NSC = 8;        // s-chunks for attention partials

typedef __attribute__((ext_vector_type(8))) short short8;   // bf16x8 frag
typedef __attribute__((ext_vector_type(4))) short short4v;  // bf16x4
typedef __attribute__((ext_vector_type(4))) float f32x4;

// -------- workspace layout (float offsets) --------
constexpr size_t OFF_PCTX  = 0;                                   // 128*8*512
constexpr size_t OFF_PML   = OFF_PCTX  + (size_t)NB*NSC*NH;       // 2048
constexpr size_t OFF_XBF   = OFF_PML   + (size_t)NB*NSC*2;        // bf16 [128][768]
constexpr size_t OFF_H0NBF = OFF_XBF   + 49152;                   // bf16 [128][512]
constexpr size_t OFF_H1NBF = OFF_H0NBF + 32768;

// d_out layout: pred[128*32000] | new_hidden[2*128*512] | new_cell[2*128*512]
constexpr size_t OUT_HID  = (size_t)NB * NV;
constexpr size_t OUT_CELL = OUT_HID + 2ull * NB * NH;

__device__ inline float sigf(float x) { return 1.0f / (1.0f + expf(-x)); }
__device__ inline short bf16s(float x) {
  __hip_bfloat16 h = __float2bfloat16(x);
  return *reinterpret_cast<short*>(&h);
}

// -------- one-pass online-softmax attention partial, dual chain (r7) -----
__global__ __launch_bounds__(256) void attn_partial_k(
    const float* __restrict__ enc, const float* __restrict__ attn_w,
    float* __restrict__ pctx, float* __restrict__ pml) {
  const int sc = blockIdx.x, b = blockIdx.y;
  const int wv = threadIdx.x >> 6, lane = threadIdx.x & 63;
  const f32x4 wa = *reinterpret_cast<const f32x4*>(attn_w + lane * 4);
  const f32x4 wb = *reinterpret_cast<const f32x4*>(attn_w + 256 + lane * 4);
  float m0 = -INFINITY, l0 = 0.f, m1 = -INFINITY, l1 = 0.f;
  f32x4 a00 = {}, a01 = {}, a10 = {}, a11 = {};
  const float* base = enc + ((size_t)(sc * 64 + wv) * NB + b) * NH;
  for (int i = 0; i < 8; ++i) {
    const float* r0 = base + (size_t)(i * 4) * NB * NH;
    const float* r1 = base + (size_t)((i + 8) * 4) * NB * NH;
    f32x4 e00 = *reinterpret_cast<const f32x4*>(r0 + lane * 4);
    f32x4 e01 = *reinterpret_cast<const f32x4*>(r0 + 256 + lane * 4);
    f32x4 e10 = *reinterpret_cast<const f32x4*>(r1 + lane * 4);
    f32x4 e11 = *reinterpret_cast<const f32x4*>(r1 + 256 + lane * 4);
    float d0 = e00.x * wa.x + e00.y * wa.y + e00.z * wa.z + e00.w * wa.w
             + e01.x * wb.x + e01.y * wb.y + e01.z * wb.z + e01.w * wb.w;
    float d1 = e10.x * wa.x + e10.y * wa.y + e10.z * wa.z + e10.w * wa.w
             + e11.x * wb.x + e11.y * wb.y + e11.z * wb.z + e11.w * wb.w;
#pragma unroll
    for (int off = 32; off; off >>= 1) {
      d0 += __shfl_xor(d0, off);
      d1 += __shfl_xor(d1, off);
    }
    float mn0 = fmaxf(m0, d0), mn1 = fmaxf(m1, d1);
    float s0 = expf(m0 - mn0), s1 = expf(m1 - mn1);
    float p0 = expf(d0 - mn0), p1 = expf(d1 - mn1);
    l0 = l0 * s0 + p0;         l1 = l1 * s1 + p1;
    a00 = a00 * s0 + p0 * e00; a01 = a01 * s0 + p0 * e01;
    a10 = a10 * s1 + p1 * e10; a11 = a11 * s1 + p1 * e11;
    m0 = mn0; m1 = mn1;
  }
  const float Mw = fmaxf(m0, m1);
  const float c0 = expf(m0 - Mw), c1 = expf(m1 - Mw);
  const float lw = l0 * c0 + l1 * c1;
  const f32x4 accA = a00 * c0 + a10 * c1;
  const f32x4 accB = a01 * c0 + a11 * c1;
  __shared__ float sm[4], sl[4], sacc[4][NH];
  if (lane == 0) { sm[wv] = Mw; sl[wv] = lw; }
  *reinterpret_cast<f32x4*>(&sacc[wv][lane * 4]) = accA;
  *reinterpret_cast<f32x4*>(&sacc[wv][256 + lane * 4]) = accB;
  __syncthreads();
  const float M = fmaxf(fmaxf(sm[0], sm[1]), fmaxf(sm[2], sm[3]));
  const float e0 = expf(sm[0] - M), e1 = expf(sm[1] - M),
              e2 = expf(sm[2] - M), e3 = expf(sm[3] - M);
  const int t = threadIdx.x;
  float* outc = pctx + ((size_t)b * NSC + sc) * NH;
#pragma unroll
  for (int q = 0; q < 2; ++q) {
    int h = q * 256 + t;
    outc[h] = sacc[0][h] * e0 + sacc[1][h] * e1 + sacc[2][h] * e2 + sacc[3][h] * e3;
  }
  if (t == 0) {
    pml[((size_t)b * NSC + sc) * 2 + 0] = M;
    pml[((size_t)b * NSC + sc) * 2 + 1] = sl[0] * e0 + sl[1] * e1 + sl[2] * e2 + sl[3] * e3;
  }
}

// -------- merge chunk partials, normalize, emit bf16 x (+embedding) ------
__global__ __launch_bounds__(256) void attn_finish_k(
    const float* __restrict__ pctx, const float* __restrict__ pml,
    const float* __restrict__ emb, const int* __restrict__ dec,
    __hip_bfloat16* __restrict__ xbf) {
  const int b = blockIdx.x, t = threadIdx.x;
  float ms[NSC];
  float M = -INFINITY;
#pragma unroll
  for (int sc = 0; sc < NSC; ++sc) {
    ms[sc] = pml[((size_t)b * NSC + sc) * 2 + 0];
    M = fmaxf(M, ms[sc]);
  }
  float L = 0.f, es[NSC];
#pragma unroll
  for (int sc = 0; sc < NSC; ++sc) {
    es[sc] = expf(ms[sc] - M);
    L += pml[((size_t)b * NSC + sc) * 2 + 1] * es[sc];
  }
  const float invL = 1.f / L;
#pragma unroll
  for (int q = 0; q < 2; ++q) {
    int h = q * 256 + t;
    float v = 0.f;
#pragma unroll
    for (int sc = 0; sc < NSC; ++sc)
      v += pctx[((size_t)b * NSC + sc) * NH + h] * es[sc];
    xbf[(size_t)b * NX + h] = __float2bfloat16(v * invL);
  }
  xbf[(size_t)b * NX + NH + t] = __float2bfloat16(emb[(size_t)dec[b] * NE + t]);
}

// -------- fused LSTM layer (r7-proven): 256 blocks x 8 waves --------
__global__ __launch_bounds__(512) void fused_lstm_k(
    const __hip_bfloat16* __restrict__ Abf, int strideA, int K0,
    const float* __restrict__ Wih,
    const float* __restrict__ hf32, const float* __restrict__ Whh,
    const float* __restrict__ b_ih, const float* __restrict__ b_hh,
    const float* __restrict__ c_in,
    float* __restrict__ h_out, float* __restrict__ c_out,
    __hip_bfloat16* __restrict__ hbf_out) {
  const int wid = threadIdx.x >> 6, lane = threadIdx.x & 63;
  const int gate = wid & 3, part = wid >> 2;
  const int l15 = lane & 15, lhi = lane >> 4;
  const int mtile = blockIdx.x >> 5, h16 = blockIdx.x & 31;
  const int n = gate * NH + h16 * 16 + l15;
  f32x4 acc = {};
  if (part == 0) {
    const float* wrow = Wih + (size_t)n * K0 + lhi * 8;
    const __hip_bfloat16* arow = Abf + (size_t)(mtile * 16 + l15) * strideA + lhi * 8;
#pragma unroll 4
    for (int k0 = 0; k0 < K0; k0 += 32) {
      f32x4 w0 = *reinterpret_cast<const f32x4*>(wrow + k0);
      f32x4 w1 = *reinterpret_cast<const f32x4*>(wrow + k0 + 4);
      short8 bfrag;
      bfrag[0] = bf16s(w0.x); bfrag[1] = bf16s(w0.y);
      bfrag[2] = bf16s(w0.z); bfrag[3] = bf16s(w0.w);
      bfrag[4] = bf16s(w1.x); bfrag[5] = bf16s(w1.y);
      bfrag[6] = bf16s(w1.z); bfrag[7] = bf16s(w1.w);
      short8 afrag = *reinterpret_cast<const short8*>(arow + k0);
      acc = __builtin_amdgcn_mfma_f32_16x16x32_bf16(afrag, bfrag, acc, 0, 0, 0);
    }
  } else {
    const float* wrow = Whh + (size_t)n * NH + lhi * 8;
    const float* arow = hf32 + (size_t)(mtile * 16 + l15) * NH + lhi * 8;
#pragma unroll 4
    for (int k0 = 0; k0 < NH; k0 += 32) {
      f32x4 w0 = *reinterpret_cast<const f32x4*>(wrow + k0);
      f32x4 w1 = *reinterpret_cast<const f32x4*>(wrow + k0 + 4);
      f32x4 a0 = *reinterpret_cast<const f32x4*>(arow + k0);
      f32x4 a1 = *reinterpret_cast<const f32x4*>(arow + k0 + 4);
      short8 bfrag, afrag;
      bfrag[0] = bf16s(w0.x); bfrag[1] = bf16s(w0.y);
      bfrag[2] = bf16s(w0.z); bfrag[3] = bf16s(w0.w);
      bfrag[4] = bf16s(w1.x); bfrag[5] = bf16s(w1.y);
      bfrag[6] = bf16s(w1.z); bfrag[7] = bf16s(w1.w);
      afrag[0] = bf16s(a0.x); afrag[1] = bf16s(a0.y);
      afrag[2] = bf16s(a0.z); afrag[3] = bf16s(a0.w);
      afrag[4] = bf16s(a1.x); afrag[5] = bf16s(a1.y);
      afrag[6] = bf16s(a1.z); afrag[7] = bf16s(a1.w);
      acc = __builtin_amdgcn_mfma_f32_16x16x32_bf16(afrag, bfrag, acc, 0, 0, 0);
    }
  }
  __shared__ float sg[8][16][17];
#pragma unroll
  for (int r = 0; r < 4; ++r) sg[wid][lhi * 4 + r][l15] = acc[r];
  __syncthreads();
  const int t = threadIdx.x;
  if (t < 256) {
    const int row = t >> 4, col = t & 15;
    const int b = mtile * 16 + row, h = h16 * 16 + col;
    float ig = sg[0][row][col] + sg[4][row][col] + b_ih[0 * NH + h] + b_hh[0 * NH + h];
    float fg = sg[1][row][col] + sg[5][row][col] + b_ih[1 * NH + h] + b_hh[1 * NH + h];
    float gg = sg[2][row][col] + sg[6][row][col] + b_ih[2 * NH + h] + b_hh[2 * NH + h];
    float og = sg[3][row][col] + sg[7][row][col] + b_ih[3 * NH + h] + b_hh[3 * NH + h];
    float c = c_in[(size_t)b * NH + h];
    float c2 = sigf(fg) * c + sigf(ig) * tanhf(gg);
    float h2 = sigf(og) * tanhf(c2);
    c_out[(size_t)b * NH + h] = c2;
    h_out[(size_t)b * NH + h] = h2;
    hbf_out[(size_t)b * NH + h] = __float2bfloat16(h2);
  }
}

// -------- FC: pipelined persistent-panel GEMM (r15-proven, 8 panels) -----
constexpr int FC_PANELS = 8;
constexpr int FC_BLOCKS = NV / (16 * FC_PANELS);   // 250
constexpr int SLAB = 520;                          // shorts per ks slab

__global__ __launch_bounds__(256, 1) void gemm_fc_pipe_k(
    const __hip_bfloat16* __restrict__ Abf, const float* __restrict__ W,
    const float* __restrict__ bias, float* __restrict__ out) {
  __shared__ short wlds[2][16 * SLAB];   // ~16.3 KB per buffer
  const int tid = threadIdx.x, wv = tid >> 6, lane = tid & 63;
  const int l15 = lane & 15, lhi = lane >> 4;
  const int nbase = blockIdx.x * (16 * FC_PANELS);

  int soff[8];
#pragma unroll
  for (int i = 0; i < 8; ++i) {
    const int o = i * 1024 + tid * 4;
    const int n = o >> 9, kk = o & 511;
    soff[i] = (kk >> 5) * SLAB + n * 32 + (kk & 31);
  }

  short8 af[2][16];
#pragma unroll
  for (int m = 0; m < 2; ++m) {
    const __hip_bfloat16* ar = Abf + (size_t)(wv * 32 + m * 16 + l15) * NH + lhi * 8;
#pragma unroll
    for (int ks = 0; ks < 16; ++ks)
      af[m][ks] = *reinterpret_cast<const short8*>(ar + ks * 32);
  }

  f32x4 wr[8];
  {
    const float* panel = W + (size_t)nbase * NH;
#pragma unroll
    for (int i = 0; i < 8; ++i)
      wr[i] = *reinterpret_cast<const f32x4*>(panel + i * 1024 + tid * 4);
    short* wb0 = wlds[0];
#pragma unroll
    for (int i = 0; i < 8; ++i) {
      short4v cv;
      cv[0] = bf16s(wr[i].x); cv[1] = bf16s(wr[i].y);
      cv[2] = bf16s(wr[i].z); cv[3] = bf16s(wr[i].w);
      *reinterpret_cast<short4v*>(wb0 + soff[i]) = cv;
    }
  }
  __syncthreads();

  f32x4 s0 = {}, s1 = {};
  int sn0 = -1;
  for (int p = 0; p < FC_PANELS; ++p) {
    if (p < FC_PANELS - 1) {
      const float* panel = W + (size_t)(nbase + (p + 1) * 16) * NH;
#pragma unroll
      for (int i = 0; i < 8; ++i)
        wr[i] = *reinterpret_cast<const f32x4*>(panel + i * 1024 + tid * 4);
    }
    if (sn0 >= 0) {
      const float bv = bias[sn0 + l15];
#pragma unroll
      for (int q = 0; q < 4; ++q) {
        out[(size_t)(wv * 32 + 0 * 16 + lhi * 4 + q) * NV + sn0 + l15] = s0[q] + bv;
        out[(size_t)(wv * 32 + 1 * 16 + lhi * 4 + q) * NV + sn0 + l15] = s1[q] + bv;
      }
    }
    {
      const short* wb = wlds[p & 1];
      f32x4 a0 = {}, a1 = {};
#pragma unroll
      for (int ks = 0; ks < 16; ++ks) {
        short8 bf = *reinterpret_cast<const short8*>(wb + ks * SLAB + l15 * 32 + lhi * 8);
        a0 = __builtin_amdgcn_mfma_f32_16x16x32_bf16(af[0][ks], bf, a0, 0, 0, 0);
        a1 = __builtin_amdgcn_mfma_f32_16x16x32_bf16(af[1][ks], bf, a1, 0, 0, 0);
      }
      s0 = a0; s1 = a1; sn0 = nbase + p * 16;
    }
    if (p < FC_PANELS - 1) {
      short* wbn = wlds[(p + 1) & 1];
#pragma unroll
      for (int i = 0; i < 8; ++i) {
        short4v cv;
        cv[0] = bf16s(wr[i].x); cv[1] = bf16s(wr[i].y);
        cv[2] = bf16s(wr[i].z); cv[3] = bf16s(wr[i].w);
        *reinterpret_cast<short4v*>(wbn + soff[i]) = cv;
      }
      __syncthreads();
    }
  }
  {
    const float bv = bias[sn0 + l15];
#pragma unroll
    for (int q = 0; q < 4; ++q) {
      out[(size_t)(wv * 32 + 0 * 16 + lhi * 4 + q) * NV + sn0 + l15] = s0[q] + bv;
      out[(size_t)(wv * 32 + 1 * 16 + lhi * 4 + q) * NV + sn0 + l15] = s1[q] + bv;
    }
  }
}

extern "C" void kernel_launch(void* const* d_in, const int* in_sizes, int n_in,
                              void* d_out, int out_size, void* d_ws, size_t ws_size,
                              hipStream_t stream) {
  const int*   dec    = (const int*)d_in[0];
  const float* hidden = (const float*)d_in[1];
  const float* cell   = (const float*)d_in[2];
  const float* enc    = (const float*)d_in[3];
  const float* emb    = (const float*)d_in[4];
  const float* attn_w = (const float*)d_in[5];
  // d_in[6] = attn_b (cancels in softmax)
  const float* w_ih0  = (const float*)d_in[7];
  const float* w_hh0  = (const float*)d_in[8];
  const float* b_ih0  = (const float*)d_in[9];
  const float* b_hh0  = (const float*)d_in[10];
  const float* w_ih1  = (const float*)d_in[11];
  const float* w_hh1  = (const float*)d_in[12];
  const float* b_ih1  = (const float*)d_in[13];
  const float* b_hh1  = (const float*)d_in[14];
  const float* fc_w   = (const float*)d_in[15];
  const float* fc_b   = (const float*)d_in[16];
  float* out = (float*)d_out;
  float* ws  = (float*)d_ws;

  float* pctx = ws + OFF_PCTX;
  float* pml  = ws + OFF_PML;
  __hip_bfloat16* xbf   = (__hip_bfloat16*)(ws + OFF_XBF);
  __hip_bfloat16* h0nbf = (__hip_bfloat16*)(ws + OFF_H0NBF);
  __hip_bfloat16* h1nbf = (__hip_bfloat16*)(ws + OFF_H1NBF);

  // TIMING PROBE: attn_partial 4x (idempotent, deterministic).
  // attn = (dur_us - 81.7)/3.
  attn_partial_k<<<dim3(NSC, NB), 256, 0, stream>>>(enc, attn_w, pctx, pml);
  attn_partial_k<<<dim3(NSC, NB), 256, 0, stream>>>(enc, attn_w, pctx, pml);
  attn_partial_k<<<dim3(NSC, NB), 256, 0, stream>>>(enc, attn_w, pctx, pml);
  attn_partial_k<<<dim3(NSC, NB), 256, 0, stream>>>(enc, attn_w, pctx, pml);
  attn_finish_k<<<NB, 256, 0, stream>>>(pctx, pml, emb, dec, xbf);
  fused_lstm_k<<<256, 512, 0, stream>>>(xbf, NX, NX, w_ih0, hidden, w_hh0,
                                        b_ih0, b_hh0, cell,
                                        out + OUT_HID, out + OUT_CELL, h0nbf);
  fused_lstm_k<<<256, 512, 0, stream>>>(h0nbf, NH, NH, w_ih1, hidden + NB * NH, w_hh1,
                                        b_ih1, b_hh1, cell + NB * NH,
                                        out + OUT_HID + (size_t)NB * NH,
                                        out + OUT_CELL + (size_t)NB * NH, h1nbf);
  gemm_fc_pipe_k<<<FC_BLOCKS, 256, 0, stream>>>(h1nbf, fc_w, fc_b, out);
}

// Round 19
// 78.533 us; speedup vs baseline: 1.8867x; 1.8867x over previous
//
#include <hip/hip_runtime.h>
#include <hip/hip_bf16.h>
#include <math.h>

constexpr int NV = 32000;
constexpr int NE = 256;
constexpr int NH = 512;
constexpr int NB = 128;
constexpr int NS = 512;
constexpr int NX = NH + NE;   // 768, LSTM0 input dim
constexpr int NG = 2048;      // gate rows per layer
constexpr int NSC = 8;        // s-chunks for attention partials

typedef __attribute__((ext_vector_type(8))) short short8;   // bf16x8 frag
typedef __attribute__((ext_vector_type(4))) short short4v;  // bf16x4
typedef __attribute__((ext_vector_type(4))) float f32x4;

// -------- workspace layout (float offsets) --------
constexpr size_t OFF_PCTX  = 0;                               // 524288
constexpr size_t OFF_PML   = OFF_PCTX  + (size_t)NB*NSC*NH;   // 2048
constexpr size_t OFF_XBF   = OFF_PML   + (size_t)NB*NSC*2;    // bf16 [128][768] = 49152 slots
constexpr size_t OFF_H0NBF = OFF_XBF   + 49152;               // bf16 [128][512] = 32768 slots
constexpr size_t OFF_H1NBF = OFF_H0NBF + 32768;
constexpr size_t OFF_H0BFI = OFF_H1NBF + 32768;               // bf16 copy of hidden[0]
constexpr size_t OFF_H1BFI = OFF_H0BFI + 32768;               // bf16 copy of hidden[1]
constexpr size_t OFF_GBUF  = OFF_H1BFI + 32768;               // f32 [128][2048]

// d_out layout: pred[128*32000] | new_hidden[2*128*512] | new_cell[2*128*512]
constexpr size_t OUT_HID  = (size_t)NB * NV;
constexpr size_t OUT_CELL = OUT_HID + 2ull * NB * NH;

__device__ inline float sigf(float x) { return 1.0f / (1.0f + expf(-x)); }
__device__ inline short bf16s(float x) {
  __hip_bfloat16 h = __float2bfloat16(x);
  return *reinterpret_cast<short*>(&h);
}

// -------- one-pass online-softmax attention partial, dual chain (r7) -----
__global__ __launch_bounds__(256) void attn_partial_k(
    const float* __restrict__ enc, const float* __restrict__ attn_w,
    float* __restrict__ pctx, float* __restrict__ pml) {
  const int sc = blockIdx.x, b = blockIdx.y;
  const int wv = threadIdx.x >> 6, lane = threadIdx.x & 63;
  const f32x4 wa = *reinterpret_cast<const f32x4*>(attn_w + lane * 4);
  const f32x4 wb = *reinterpret_cast<const f32x4*>(attn_w + 256 + lane * 4);
  float m0 = -INFINITY, l0 = 0.f, m1 = -INFINITY, l1 = 0.f;
  f32x4 a00 = {}, a01 = {}, a10 = {}, a11 = {};
  const float* base = enc + ((size_t)(sc * 64 + wv) * NB + b) * NH;
  for (int i = 0; i < 8; ++i) {
    const float* r0 = base + (size_t)(i * 4) * NB * NH;
    const float* r1 = base + (size_t)((i + 8) * 4) * NB * NH;
    f32x4 e00 = *reinterpret_cast<const f32x4*>(r0 + lane * 4);
    f32x4 e01 = *reinterpret_cast<const f32x4*>(r0 + 256 + lane * 4);
    f32x4 e10 = *reinterpret_cast<const f32x4*>(r1 + lane * 4);
    f32x4 e11 = *reinterpret_cast<const f32x4*>(r1 + 256 + lane * 4);
    float d0 = e00.x * wa.x + e00.y * wa.y + e00.z * wa.z + e00.w * wa.w
             + e01.x * wb.x + e01.y * wb.y + e01.z * wb.z + e01.w * wb.w;
    float d1 = e10.x * wa.x + e10.y * wa.y + e10.z * wa.z + e10.w * wa.w
             + e11.x * wb.x + e11.y * wb.y + e11.z * wb.z + e11.w * wb.w;
#pragma unroll
    for (int off = 32; off; off >>= 1) {
      d0 += __shfl_xor(d0, off);
      d1 += __shfl_xor(d1, off);
    }
    float mn0 = fmaxf(m0, d0), mn1 = fmaxf(m1, d1);
    float s0 = expf(m0 - mn0), s1 = expf(m1 - mn1);
    float p0 = expf(d0 - mn0), p1 = expf(d1 - mn1);
    l0 = l0 * s0 + p0;         l1 = l1 * s1 + p1;
    a00 = a00 * s0 + p0 * e00; a01 = a01 * s0 + p0 * e01;
    a10 = a10 * s1 + p1 * e10; a11 = a11 * s1 + p1 * e11;
    m0 = mn0; m1 = mn1;
  }
  const float Mw = fmaxf(m0, m1);
  const float c0 = expf(m0 - Mw), c1 = expf(m1 - Mw);
  const float lw = l0 * c0 + l1 * c1;
  const f32x4 accA = a00 * c0 + a10 * c1;
  const f32x4 accB = a01 * c0 + a11 * c1;
  __shared__ float sm[4], sl[4], sacc[4][NH];
  if (lane == 0) { sm[wv] = Mw; sl[wv] = lw; }
  *reinterpret_cast<f32x4*>(&sacc[wv][lane * 4]) = accA;
  *reinterpret_cast<f32x4*>(&sacc[wv][256 + lane * 4]) = accB;
  __syncthreads();
  const float M = fmaxf(fmaxf(sm[0], sm[1]), fmaxf(sm[2], sm[3]));
  const float e0 = expf(sm[0] - M), e1 = expf(sm[1] - M),
              e2 = expf(sm[2] - M), e3 = expf(sm[3] - M);
  const int t = threadIdx.x;
  float* outc = pctx + ((size_t)b * NSC + sc) * NH;
#pragma unroll
  for (int q = 0; q < 2; ++q) {
    int h = q * 256 + t;
    outc[h] = sacc[0][h] * e0 + sacc[1][h] * e1 + sacc[2][h] * e2 + sacc[3][h] * e3;
  }
  if (t == 0) {
    pml[((size_t)b * NSC + sc) * 2 + 0] = M;
    pml[((size_t)b * NSC + sc) * 2 + 1] = sl[0] * e0 + sl[1] * e1 + sl[2] * e2 + sl[3] * e3;
  }
}

// -------- merge partials, emit bf16 x (+embedding) + bf16 hidden copies --
__global__ __launch_bounds__(256) void attn_finish_k(
    const float* __restrict__ pctx, const float* __restrict__ pml,
    const float* __restrict__ emb, const int* __restrict__ dec,
    const float* __restrict__ hidden,
    __hip_bfloat16* __restrict__ xbf,
    __hip_bfloat16* __restrict__ h0bf, __hip_bfloat16* __restrict__ h1bf) {
  const int b = blockIdx.x, t = threadIdx.x;
  float ms[NSC];
  float M = -INFINITY;
#pragma unroll
  for (int sc = 0; sc < NSC; ++sc) {
    ms[sc] = pml[((size_t)b * NSC + sc) * 2 + 0];
    M = fmaxf(M, ms[sc]);
  }
  float L = 0.f, es[NSC];
#pragma unroll
  for (int sc = 0; sc < NSC; ++sc) {
    es[sc] = expf(ms[sc] - M);
    L += pml[((size_t)b * NSC + sc) * 2 + 1] * es[sc];
  }
  const float invL = 1.f / L;
#pragma unroll
  for (int q = 0; q < 2; ++q) {
    int h = q * 256 + t;
    float v = 0.f;
#pragma unroll
    for (int sc = 0; sc < NSC; ++sc)
      v += pctx[((size_t)b * NSC + sc) * NH + h] * es[sc];
    xbf[(size_t)b * NX + h] = __float2bfloat16(v * invL);
    // bf16 copies of the previous hidden states (LSTM h-operands)
    h0bf[(size_t)b * NH + h] = __float2bfloat16(hidden[(size_t)b * NH + h]);
    h1bf[(size_t)b * NH + h] =
        __float2bfloat16(hidden[(size_t)(NB * NH) + (size_t)b * NH + h]);
  }
  xbf[(size_t)b * NX + NH + t] = __float2bfloat16(emb[(size_t)dec[b] * NE + t]);
}

// -------- LSTM gates GEMM: pipelined panel, weights read ONCE ------------
// 128 blocks; block p owns gate-rows [p*16,p*16+16) x all M=128.
// K chunked 256 floats: NCHX chunks from (Wx,Ax), then 2 from (Wh,Ah).
// Double-buffered LDS bf16 panel [ks(8)][n(16)][kk(32)] slab 520.
constexpr int LSLAB = 520;
__global__ __launch_bounds__(256, 1) void lstm_gemm_k(
    const float* __restrict__ Wx, int Kx, const float* __restrict__ Wh,
    const __hip_bfloat16* __restrict__ Ax, const __hip_bfloat16* __restrict__ Ah,
    float* __restrict__ gbuf) {
  __shared__ short wlds[2][8 * LSLAB];
  const int tid = threadIdx.x, wv = tid >> 6, lane = tid & 63;
  const int l15 = lane & 15, lhi = lane >> 4;
  const int n0 = blockIdx.x * 16;
  const int NCHX = Kx >> 8, NCH = NCHX + 2;
  const int srow = tid >> 6;            // + i*4
  const int scol = lane * 4;            // 0..252
  const int soff0 = (scol >> 5) * LSLAB + (scol & 31);   // + n*32

  f32x4 wr[4];
#define LSTAGE_LOAD(c)                                                        \
  {                                                                           \
    const bool fx = (c) < NCHX;                                               \
    const float* Ws = fx ? Wx : Wh;                                           \
    const int Ks = fx ? Kx : NH;                                              \
    const int cb = fx ? (c) * 256 : ((c) - NCHX) * 256;                       \
    _Pragma("unroll")                                                         \
    for (int i = 0; i < 4; ++i)                                               \
      wr[i] = *reinterpret_cast<const f32x4*>(                                \
          Ws + (size_t)(n0 + i * 4 + srow) * Ks + cb + scol);                 \
  }
#define LSTAGE_WRITE(buf)                                                     \
  {                                                                           \
    _Pragma("unroll")                                                         \
    for (int i = 0; i < 4; ++i) {                                             \
      short4v cv;                                                             \
      cv[0] = bf16s(wr[i].x); cv[1] = bf16s(wr[i].y);                         \
      cv[2] = bf16s(wr[i].z); cv[3] = bf16s(wr[i].w);                         \
      *reinterpret_cast<short4v*>((buf) + soff0 + (i * 4 + srow) * 32) = cv;  \
    }                                                                         \
  }

  LSTAGE_LOAD(0);
  LSTAGE_WRITE(wlds[0]);
  __syncthreads();

  f32x4 acc0 = {}, acc1 = {};
  for (int c = 0; c < NCH; ++c) {
    if (c + 1 < NCH) LSTAGE_LOAD(c + 1);
    {
      const bool fx = c < NCHX;
      const __hip_bfloat16* As = fx ? Ax : Ah;
      const int Ks = fx ? Kx : NH;
      const int cb = fx ? c * 256 : (c - NCHX) * 256;
      const short* wb = wlds[c & 1];
      const __hip_bfloat16* ar0 = As + (size_t)(wv * 32 + l15) * Ks + cb + lhi * 8;
      const __hip_bfloat16* ar1 = ar0 + (size_t)16 * Ks;
#pragma unroll
      for (int ks = 0; ks < 8; ++ks) {
        short8 bf = *reinterpret_cast<const short8*>(wb + ks * LSLAB + l15 * 32 + lhi * 8);
        short8 a0 = *reinterpret_cast<const short8*>(ar0 + ks * 32);
        short8 a1 = *reinterpret_cast<const short8*>(ar1 + ks * 32);
        acc0 = __builtin_amdgcn_mfma_f32_16x16x32_bf16(a0, bf, acc0, 0, 0, 0);
        acc1 = __builtin_amdgcn_mfma_f32_16x16x32_bf16(a1, bf, acc1, 0, 0, 0);
      }
    }
    if (c + 1 < NCH) {
      LSTAGE_WRITE(wlds[(c + 1) & 1]);
      __syncthreads();
    }
  }
#pragma unroll
  for (int q = 0; q < 4; ++q) {
    gbuf[(size_t)(wv * 32 + lhi * 4 + q) * NG + n0 + l15] = acc0[q];
    gbuf[(size_t)(wv * 32 + 16 + lhi * 4 + q) * NG + n0 + l15] = acc1[q];
  }
#undef LSTAGE_LOAD
#undef LSTAGE_WRITE
}

// -------- LSTM pointwise: bias + activations + outputs -------------------
__global__ __launch_bounds__(256) void lstm_point_k(
    const float* __restrict__ g, const float* __restrict__ b_ih,
    const float* __restrict__ b_hh, const float* __restrict__ c_in,
    float* __restrict__ h_out, float* __restrict__ c_out,
    __hip_bfloat16* __restrict__ hbf_out) {
  const int idx = blockIdx.x * 256 + threadIdx.x;   // 65536
  const int h = idx & 511;
  const size_t base = (size_t)(idx >> 9) * NG;
  float ig = g[base + 0 * NH + h] + b_ih[0 * NH + h] + b_hh[0 * NH + h];
  float fg = g[base + 1 * NH + h] + b_ih[1 * NH + h] + b_hh[1 * NH + h];
  float gg = g[base + 2 * NH + h] + b_ih[2 * NH + h] + b_hh[2 * NH + h];
  float og = g[base + 3 * NH + h] + b_ih[3 * NH + h] + b_hh[3 * NH + h];
  float c = c_in[idx];
  float c2 = sigf(fg) * c + sigf(ig) * tanhf(gg);
  float h2 = sigf(og) * tanhf(c2);
  c_out[idx] = c2;
  h_out[idx] = h2;
  hbf_out[idx] = __float2bfloat16(h2);
}

// -------- FC: pipelined persistent-panel GEMM (r15-proven, 8 panels) -----
constexpr int FC_PANELS = 8;
constexpr int FC_BLOCKS = NV / (16 * FC_PANELS);   // 250
constexpr int SLAB = 520;                          // shorts per ks slab

__global__ __launch_bounds__(256, 1) void gemm_fc_pipe_k(
    const __hip_bfloat16* __restrict__ Abf, const float* __restrict__ W,
    const float* __restrict__ bias, float* __restrict__ out) {
  __shared__ short wlds[2][16 * SLAB];   // ~16.3 KB per buffer
  const int tid = threadIdx.x, wv = tid >> 6, lane = tid & 63;
  const int l15 = lane & 15, lhi = lane >> 4;
  const int nbase = blockIdx.x * (16 * FC_PANELS);

  int soff[8];
#pragma unroll
  for (int i = 0; i < 8; ++i) {
    const int o = i * 1024 + tid * 4;
    const int n = o >> 9, kk = o & 511;
    soff[i] = (kk >> 5) * SLAB + n * 32 + (kk & 31);
  }

  short8 af[2][16];
#pragma unroll
  for (int m = 0; m < 2; ++m) {
    const __hip_bfloat16* ar = Abf + (size_t)(wv * 32 + m * 16 + l15) * NH + lhi * 8;
#pragma unroll
    for (int ks = 0; ks < 16; ++ks)
      af[m][ks] = *reinterpret_cast<const short8*>(ar + ks * 32);
  }

  f32x4 wr[8];
  {
    const float* panel = W + (size_t)nbase * NH;
#pragma unroll
    for (int i = 0; i < 8; ++i)
      wr[i] = *reinterpret_cast<const f32x4*>(panel + i * 1024 + tid * 4);
    short* wb0 = wlds[0];
#pragma unroll
    for (int i = 0; i < 8; ++i) {
      short4v cv;
      cv[0] = bf16s(wr[i].x); cv[1] = bf16s(wr[i].y);
      cv[2] = bf16s(wr[i].z); cv[3] = bf16s(wr[i].w);
      *reinterpret_cast<short4v*>(wb0 + soff[i]) = cv;
    }
  }
  __syncthreads();

  f32x4 s0 = {}, s1 = {};
  int sn0 = -1;
  for (int p = 0; p < FC_PANELS; ++p) {
    if (p < FC_PANELS - 1) {
      const float* panel = W + (size_t)(nbase + (p + 1) * 16) * NH;
#pragma unroll
      for (int i = 0; i < 8; ++i)
        wr[i] = *reinterpret_cast<const f32x4*>(panel + i * 1024 + tid * 4);
    }
    if (sn0 >= 0) {
      const float bv = bias[sn0 + l15];
#pragma unroll
      for (int q = 0; q < 4; ++q) {
        out[(size_t)(wv * 32 + 0 * 16 + lhi * 4 + q) * NV + sn0 + l15] = s0[q] + bv;
        out[(size_t)(wv * 32 + 1 * 16 + lhi * 4 + q) * NV + sn0 + l15] = s1[q] + bv;
      }
    }
    {
      const short* wb = wlds[p & 1];
      f32x4 a0 = {}, a1 = {};
#pragma unroll
      for (int ks = 0; ks < 16; ++ks) {
        short8 bf = *reinterpret_cast<const short8*>(wb + ks * SLAB + l15 * 32 + lhi * 8);
        a0 = __builtin_amdgcn_mfma_f32_16x16x32_bf16(af[0][ks], bf, a0, 0, 0, 0);
        a1 = __builtin_amdgcn_mfma_f32_16x16x32_bf16(af[1][ks], bf, a1, 0, 0, 0);
      }
      s0 = a0; s1 = a1; sn0 = nbase + p * 16;
    }
    if (p < FC_PANELS - 1) {
      short* wbn = wlds[(p + 1) & 1];
#pragma unroll
      for (int i = 0; i < 8; ++i) {
        short4v cv;
        cv[0] = bf16s(wr[i].x); cv[1] = bf16s(wr[i].y);
        cv[2] = bf16s(wr[i].z); cv[3] = bf16s(wr[i].w);
        *reinterpret_cast<short4v*>(wbn + soff[i]) = cv;
      }
      __syncthreads();
    }
  }
  {
    const float bv = bias[sn0 + l15];
#pragma unroll
    for (int q = 0; q < 4; ++q) {
      out[(size_t)(wv * 32 + 0 * 16 + lhi * 4 + q) * NV + sn0 + l15] = s0[q] + bv;
      out[(size_t)(wv * 32 + 1 * 16 + lhi * 4 + q) * NV + sn0 + l15] = s1[q] + bv;
    }
  }
}

extern "C" void kernel_launch(void* const* d_in, const int* in_sizes, int n_in,
                              void* d_out, int out_size, void* d_ws, size_t ws_size,
                              hipStream_t stream) {
  const int*   dec    = (const int*)d_in[0];
  const float* hidden = (const float*)d_in[1];
  const float* cell   = (const float*)d_in[2];
  const float* enc    = (const float*)d_in[3];
  const float* emb    = (const float*)d_in[4];
  const float* attn_w = (const float*)d_in[5];
  // d_in[6] = attn_b (cancels in softmax)
  const float* w_ih0  = (const float*)d_in[7];
  const float* w_hh0  = (const float*)d_in[8];
  const float* b_ih0  = (const float*)d_in[9];
  const float* b_hh0  = (const float*)d_in[10];
  const float* w_ih1  = (const float*)d_in[11];
  const float* w_hh1  = (const float*)d_in[12];
  const float* b_ih1  = (const float*)d_in[13];
  const float* b_hh1  = (const float*)d_in[14];
  const float* fc_w   = (const float*)d_in[15];
  const float* fc_b   = (const float*)d_in[16];
  float* out = (float*)d_out;
  float* ws  = (float*)d_ws;

  float* pctx = ws + OFF_PCTX;
  float* pml  = ws + OFF_PML;
  __hip_bfloat16* xbf   = (__hip_bfloat16*)(ws + OFF_XBF);
  __hip_bfloat16* h0nbf = (__hip_bfloat16*)(ws + OFF_H0NBF);
  __hip_bfloat16* h1nbf = (__hip_bfloat16*)(ws + OFF_H1NBF);
  __hip_bfloat16* h0bf  = (__hip_bfloat16*)(ws + OFF_H0BFI);
  __hip_bfloat16* h1bf  = (__hip_bfloat16*)(ws + OFF_H1BFI);
  float* gbuf = ws + OFF_GBUF;

  attn_partial_k<<<dim3(NSC, NB), 256, 0, stream>>>(enc, attn_w, pctx, pml);
  attn_finish_k<<<NB, 256, 0, stream>>>(pctx, pml, emb, dec, hidden,
                                        xbf, h0bf, h1bf);
  lstm_gemm_k<<<NG / 16, 256, 0, stream>>>(w_ih0, NX, w_hh0, xbf, h0bf, gbuf);
  lstm_point_k<<<NB * NH / 256, 256, 0, stream>>>(gbuf, b_ih0, b_hh0, cell,
                                                  out + OUT_HID, out + OUT_CELL,
                                                  h0nbf);
  lstm_gemm_k<<<NG / 16, 256, 0, stream>>>(w_ih1, NH, w_hh1, h0nbf, h1bf, gbuf);
  lstm_point_k<<<NB * NH / 256, 256, 0, stream>>>(gbuf, b_ih1, b_hh1,
                                                  cell + NB * NH,
                                                  out + OUT_HID + (size_t)NB * NH,
                                                  out + OUT_CELL + (size_t)NB * NH,
                                                  h1nbf);
  gemm_fc_pipe_k<<<FC_BLOCKS, 256, 0, stream>>>(h1nbf, fc_w, fc_b, out);
}

// Round 20
// 76.759 us; speedup vs baseline: 1.9303x; 1.0231x over previous
//
#include <hip/hip_runtime.h>
#include <hip/hip_bf16.h>
#include <math.h>

constexpr int NV = 32000;
constexpr int NE = 256;
constexpr int NH = 512;
constexpr int NB = 128;
constexpr int NS = 512;
constexpr int NX = NH + NE;   // 768, LSTM0 input dim
constexpr int NSC = 8;        // s-chunks for attention partials

typedef __attribute__((ext_vector_type(8))) short short8;   // bf16x8 frag
typedef __attribute__((ext_vector_type(4))) short short4v;  // bf16x4
typedef __attribute__((ext_vector_type(4))) float f32x4;

// -------- workspace layout (float offsets) --------
constexpr size_t OFF_PCTX  = 0;                               // 524288
constexpr size_t OFF_PML   = OFF_PCTX  + (size_t)NB*NSC*NH;   // 2048
constexpr size_t OFF_XBF   = OFF_PML   + (size_t)NB*NSC*2;    // bf16 [128][768]
constexpr size_t OFF_H0NBF = OFF_XBF   + 49152;               // bf16 [128][512]
constexpr size_t OFF_H1NBF = OFF_H0NBF + 32768;
constexpr size_t OFF_H0BFI = OFF_H1NBF + 32768;               // bf16 copy of hidden[0]
constexpr size_t OFF_H1BFI = OFF_H0BFI + 32768;               // bf16 copy of hidden[1]

// d_out layout: pred[128*32000] | new_hidden[2*128*512] | new_cell[2*128*512]
constexpr size_t OUT_HID  = (size_t)NB * NV;
constexpr size_t OUT_CELL = OUT_HID + 2ull * NB * NH;

__device__ inline float sigf(float x) { return 1.0f / (1.0f + expf(-x)); }
__device__ inline short bf16s(float x) {
  __hip_bfloat16 h = __float2bfloat16(x);
  return *reinterpret_cast<short*>(&h);
}

// -------- one-pass online-softmax attention partial, dual chain (r7) -----
__global__ __launch_bounds__(256) void attn_partial_k(
    const float* __restrict__ enc, const float* __restrict__ attn_w,
    float* __restrict__ pctx, float* __restrict__ pml) {
  const int sc = blockIdx.x, b = blockIdx.y;
  const int wv = threadIdx.x >> 6, lane = threadIdx.x & 63;
  const f32x4 wa = *reinterpret_cast<const f32x4*>(attn_w + lane * 4);
  const f32x4 wb = *reinterpret_cast<const f32x4*>(attn_w + 256 + lane * 4);
  float m0 = -INFINITY, l0 = 0.f, m1 = -INFINITY, l1 = 0.f;
  f32x4 a00 = {}, a01 = {}, a10 = {}, a11 = {};
  const float* base = enc + ((size_t)(sc * 64 + wv) * NB + b) * NH;
  for (int i = 0; i < 8; ++i) {
    const float* r0 = base + (size_t)(i * 4) * NB * NH;
    const float* r1 = base + (size_t)((i + 8) * 4) * NB * NH;
    f32x4 e00 = *reinterpret_cast<const f32x4*>(r0 + lane * 4);
    f32x4 e01 = *reinterpret_cast<const f32x4*>(r0 + 256 + lane * 4);
    f32x4 e10 = *reinterpret_cast<const f32x4*>(r1 + lane * 4);
    f32x4 e11 = *reinterpret_cast<const f32x4*>(r1 + 256 + lane * 4);
    float d0 = e00.x * wa.x + e00.y * wa.y + e00.z * wa.z + e00.w * wa.w
             + e01.x * wb.x + e01.y * wb.y + e01.z * wb.z + e01.w * wb.w;
    float d1 = e10.x * wa.x + e10.y * wa.y + e10.z * wa.z + e10.w * wa.w
             + e11.x * wb.x + e11.y * wb.y + e11.z * wb.z + e11.w * wb.w;
#pragma unroll
    for (int off = 32; off; off >>= 1) {
      d0 += __shfl_xor(d0, off);
      d1 += __shfl_xor(d1, off);
    }
    float mn0 = fmaxf(m0, d0), mn1 = fmaxf(m1, d1);
    float s0 = expf(m0 - mn0), s1 = expf(m1 - mn1);
    float p0 = expf(d0 - mn0), p1 = expf(d1 - mn1);
    l0 = l0 * s0 + p0;         l1 = l1 * s1 + p1;
    a00 = a00 * s0 + p0 * e00; a01 = a01 * s0 + p0 * e01;
    a10 = a10 * s1 + p1 * e10; a11 = a11 * s1 + p1 * e11;
    m0 = mn0; m1 = mn1;
  }
  const float Mw = fmaxf(m0, m1);
  const float c0 = expf(m0 - Mw), c1 = expf(m1 - Mw);
  const float lw = l0 * c0 + l1 * c1;
  const f32x4 accA = a00 * c0 + a10 * c1;
  const f32x4 accB = a01 * c0 + a11 * c1;
  __shared__ float sm[4], sl[4], sacc[4][NH];
  if (lane == 0) { sm[wv] = Mw; sl[wv] = lw; }
  *reinterpret_cast<f32x4*>(&sacc[wv][lane * 4]) = accA;
  *reinterpret_cast<f32x4*>(&sacc[wv][256 + lane * 4]) = accB;
  __syncthreads();
  const float M = fmaxf(fmaxf(sm[0], sm[1]), fmaxf(sm[2], sm[3]));
  const float e0 = expf(sm[0] - M), e1 = expf(sm[1] - M),
              e2 = expf(sm[2] - M), e3 = expf(sm[3] - M);
  const int t = threadIdx.x;
  float* outc = pctx + ((size_t)b * NSC + sc) * NH;
#pragma unroll
  for (int q = 0; q < 2; ++q) {
    int h = q * 256 + t;
    outc[h] = sacc[0][h] * e0 + sacc[1][h] * e1 + sacc[2][h] * e2 + sacc[3][h] * e3;
  }
  if (t == 0) {
    pml[((size_t)b * NSC + sc) * 2 + 0] = M;
    pml[((size_t)b * NSC + sc) * 2 + 1] = sl[0] * e0 + sl[1] * e1 + sl[2] * e2 + sl[3] * e3;
  }
}

// -------- merge partials, emit bf16 x (+embedding) + bf16 hidden copies --
__global__ __launch_bounds__(256) void attn_finish_k(
    const float* __restrict__ pctx, const float* __restrict__ pml,
    const float* __restrict__ emb, const int* __restrict__ dec,
    const float* __restrict__ hidden,
    __hip_bfloat16* __restrict__ xbf,
    __hip_bfloat16* __restrict__ h0bf, __hip_bfloat16* __restrict__ h1bf) {
  const int b = blockIdx.x, t = threadIdx.x;
  float ms[NSC];
  float M = -INFINITY;
#pragma unroll
  for (int sc = 0; sc < NSC; ++sc) {
    ms[sc] = pml[((size_t)b * NSC + sc) * 2 + 0];
    M = fmaxf(M, ms[sc]);
  }
  float L = 0.f, es[NSC];
#pragma unroll
  for (int sc = 0; sc < NSC; ++sc) {
    es[sc] = expf(ms[sc] - M);
    L += pml[((size_t)b * NSC + sc) * 2 + 1] * es[sc];
  }
  const float invL = 1.f / L;
#pragma unroll
  for (int q = 0; q < 2; ++q) {
    int h = q * 256 + t;
    float v = 0.f;
#pragma unroll
    for (int sc = 0; sc < NSC; ++sc)
      v += pctx[((size_t)b * NSC + sc) * NH + h] * es[sc];
    xbf[(size_t)b * NX + h] = __float2bfloat16(v * invL);
    h0bf[(size_t)b * NH + h] = __float2bfloat16(hidden[(size_t)b * NH + h]);
    h1bf[(size_t)b * NH + h] =
        __float2bfloat16(hidden[(size_t)(NB * NH) + (size_t)b * NH + h]);
  }
  xbf[(size_t)b * NX + NH + t] = __float2bfloat16(emb[(size_t)dec[b] * NE + t]);
}

// -------- fused LSTM layer: pipelined gates GEMM + in-block pointwise ----
// 128 blocks; block p owns gate rows {g*512 + p*4 + r : g<4, r<4} (all 4
// gates for h in [p*4, p*4+4)) x all M=128. Weights read exactly once.
// K chunked 256 floats (NCHX chunks of Wx/Ax then 2 of Wh/Ah), double-
// buffered LDS bf16 panel. Epilogue: acc -> LDS, bias+activations, write
// h/c/hbf directly (no gbuf round-trip).
constexpr int LSLAB = 520;
__global__ __launch_bounds__(256, 1) void lstm_fused_k(
    const float* __restrict__ Wx, int Kx, const float* __restrict__ Wh,
    const __hip_bfloat16* __restrict__ Ax, const __hip_bfloat16* __restrict__ Ah,
    const float* __restrict__ b_ih, const float* __restrict__ b_hh,
    const float* __restrict__ c_in,
    float* __restrict__ h_out, float* __restrict__ c_out,
    __hip_bfloat16* __restrict__ hbf_out) {
  __shared__ short wlds[2][8 * LSLAB];
  __shared__ float sg[NB][17];
  const int tid = threadIdx.x, wv = tid >> 6, lane = tid & 63;
  const int l15 = lane & 15, lhi = lane >> 4;
  const int p = blockIdx.x;                  // h-range [p*4, p*4+4)
  const int NCHX = Kx >> 8, NCH = NCHX + 2;
  const int srow = tid >> 6;                 // 0..3
  const int scol = lane * 4;                 // 0..252
  const int soff0 = (scol >> 5) * LSLAB + (scol & 31);

  f32x4 wr[4];
#define LSTAGE_LOAD(c)                                                        \
  {                                                                           \
    const bool fx = (c) < NCHX;                                               \
    const float* Ws = fx ? Wx : Wh;                                           \
    const int Ks = fx ? Kx : NH;                                              \
    const int cb = fx ? (c) * 256 : ((c) - NCHX) * 256;                       \
    _Pragma("unroll")                                                         \
    for (int i = 0; i < 4; ++i)                                               \
      wr[i] = *reinterpret_cast<const f32x4*>(                                \
          Ws + (size_t)(i * NH + p * 4 + srow) * Ks + cb + scol);             \
  }
#define LSTAGE_WRITE(buf)                                                     \
  {                                                                           \
    _Pragma("unroll")                                                         \
    for (int i = 0; i < 4; ++i) {                                             \
      short4v cv;                                                             \
      cv[0] = bf16s(wr[i].x); cv[1] = bf16s(wr[i].y);                         \
      cv[2] = bf16s(wr[i].z); cv[3] = bf16s(wr[i].w);                         \
      *reinterpret_cast<short4v*>((buf) + soff0 + (i * 4 + srow) * 32) = cv;  \
    }                                                                         \
  }

  LSTAGE_LOAD(0);
  LSTAGE_WRITE(wlds[0]);
  __syncthreads();

  f32x4 acc0 = {}, acc1 = {};
  for (int c = 0; c < NCH; ++c) {
    if (c + 1 < NCH) LSTAGE_LOAD(c + 1);
    {
      const bool fx = c < NCHX;
      const __hip_bfloat16* As = fx ? Ax : Ah;
      const int Ks = fx ? Kx : NH;
      const int cb = fx ? c * 256 : (c - NCHX) * 256;
      const short* wb = wlds[c & 1];
      const __hip_bfloat16* ar0 = As + (size_t)(wv * 32 + l15) * Ks + cb + lhi * 8;
      const __hip_bfloat16* ar1 = ar0 + (size_t)16 * Ks;
#pragma unroll
      for (int ks = 0; ks < 8; ++ks) {
        short8 bf = *reinterpret_cast<const short8*>(wb + ks * LSLAB + l15 * 32 + lhi * 8);
        short8 a0 = *reinterpret_cast<const short8*>(ar0 + ks * 32);
        short8 a1 = *reinterpret_cast<const short8*>(ar1 + ks * 32);
        acc0 = __builtin_amdgcn_mfma_f32_16x16x32_bf16(a0, bf, acc0, 0, 0, 0);
        acc1 = __builtin_amdgcn_mfma_f32_16x16x32_bf16(a1, bf, acc1, 0, 0, 0);
      }
    }
    if (c + 1 < NCH) {
      LSTAGE_WRITE(wlds[(c + 1) & 1]);
      __syncthreads();
    }
  }
  // acc -> LDS: sg[m][j], j = gate*4 + r (lane l15), m = M row
#pragma unroll
  for (int q = 0; q < 4; ++q) {
    sg[wv * 32 + lhi * 4 + q][l15] = acc0[q];
    sg[wv * 32 + 16 + lhi * 4 + q][l15] = acc1[q];
  }
  __syncthreads();
  // pointwise: 512 items (b, r); thread handles 2
#pragma unroll
  for (int it = 0; it < 2; ++it) {
    const int item = tid + it * 256;
    const int b = item >> 2, r = item & 3;
    const int h = p * 4 + r;
    float ig = sg[b][0 + r]  + b_ih[0 * NH + h] + b_hh[0 * NH + h];
    float fg = sg[b][4 + r]  + b_ih[1 * NH + h] + b_hh[1 * NH + h];
    float gg = sg[b][8 + r]  + b_ih[2 * NH + h] + b_hh[2 * NH + h];
    float og = sg[b][12 + r] + b_ih[3 * NH + h] + b_hh[3 * NH + h];
    float c = c_in[(size_t)b * NH + h];
    float c2 = sigf(fg) * c + sigf(ig) * tanhf(gg);
    float h2 = sigf(og) * tanhf(c2);
    c_out[(size_t)b * NH + h] = c2;
    h_out[(size_t)b * NH + h] = h2;
    hbf_out[(size_t)b * NH + h] = __float2bfloat16(h2);
  }
#undef LSTAGE_LOAD
#undef LSTAGE_WRITE
}

// -------- FC: pipelined persistent-panel GEMM (r15-proven, 8 panels) -----
constexpr int FC_PANELS = 8;
constexpr int FC_BLOCKS = NV / (16 * FC_PANELS);   // 250
constexpr int SLAB = 520;                          // shorts per ks slab

__global__ __launch_bounds__(256, 1) void gemm_fc_pipe_k(
    const __hip_bfloat16* __restrict__ Abf, const float* __restrict__ W,
    const float* __restrict__ bias, float* __restrict__ out) {
  __shared__ short wlds[2][16 * SLAB];   // ~16.3 KB per buffer
  const int tid = threadIdx.x, wv = tid >> 6, lane = tid & 63;
  const int l15 = lane & 15, lhi = lane >> 4;
  const int nbase = blockIdx.x * (16 * FC_PANELS);

  int soff[8];
#pragma unroll
  for (int i = 0; i < 8; ++i) {
    const int o = i * 1024 + tid * 4;
    const int n = o >> 9, kk = o & 511;
    soff[i] = (kk >> 5) * SLAB + n * 32 + (kk & 31);
  }

  short8 af[2][16];
#pragma unroll
  for (int m = 0; m < 2; ++m) {
    const __hip_bfloat16* ar = Abf + (size_t)(wv * 32 + m * 16 + l15) * NH + lhi * 8;
#pragma unroll
    for (int ks = 0; ks < 16; ++ks)
      af[m][ks] = *reinterpret_cast<const short8*>(ar + ks * 32);
  }

  f32x4 wr[8];
  {
    const float* panel = W + (size_t)nbase * NH;
#pragma unroll
    for (int i = 0; i < 8; ++i)
      wr[i] = *reinterpret_cast<const f32x4*>(panel + i * 1024 + tid * 4);
    short* wb0 = wlds[0];
#pragma unroll
    for (int i = 0; i < 8; ++i) {
      short4v cv;
      cv[0] = bf16s(wr[i].x); cv[1] = bf16s(wr[i].y);
      cv[2] = bf16s(wr[i].z); cv[3] = bf16s(wr[i].w);
      *reinterpret_cast<short4v*>(wb0 + soff[i]) = cv;
    }
  }
  __syncthreads();

  f32x4 s0 = {}, s1 = {};
  int sn0 = -1;
  for (int p = 0; p < FC_PANELS; ++p) {
    if (p < FC_PANELS - 1) {
      const float* panel = W + (size_t)(nbase + (p + 1) * 16) * NH;
#pragma unroll
      for (int i = 0; i < 8; ++i)
        wr[i] = *reinterpret_cast<const f32x4*>(panel + i * 1024 + tid * 4);
    }
    if (sn0 >= 0) {
      const float bv = bias[sn0 + l15];
#pragma unroll
      for (int q = 0; q < 4; ++q) {
        out[(size_t)(wv * 32 + 0 * 16 + lhi * 4 + q) * NV + sn0 + l15] = s0[q] + bv;
        out[(size_t)(wv * 32 + 1 * 16 + lhi * 4 + q) * NV + sn0 + l15] = s1[q] + bv;
      }
    }
    {
      const short* wb = wlds[p & 1];
      f32x4 a0 = {}, a1 = {};
#pragma unroll
      for (int ks = 0; ks < 16; ++ks) {
        short8 bf = *reinterpret_cast<const short8*>(wb + ks * SLAB + l15 * 32 + lhi * 8);
        a0 = __builtin_amdgcn_mfma_f32_16x16x32_bf16(af[0][ks], bf, a0, 0, 0, 0);
        a1 = __builtin_amdgcn_mfma_f32_16x16x32_bf16(af[1][ks], bf, a1, 0, 0, 0);
      }
      s0 = a0; s1 = a1; sn0 = nbase + p * 16;
    }
    if (p < FC_PANELS - 1) {
      short* wbn = wlds[(p + 1) & 1];
#pragma unroll
      for (int i = 0; i < 8; ++i) {
        short4v cv;
        cv[0] = bf16s(wr[i].x); cv[1] = bf16s(wr[i].y);
        cv[2] = bf16s(wr[i].z); cv[3] = bf16s(wr[i].w);
        *reinterpret_cast<short4v*>(wbn + soff[i]) = cv;
      }
      __syncthreads();
    }
  }
  {
    const float bv = bias[sn0 + l15];
#pragma unroll
    for (int q = 0; q < 4; ++q) {
      out[(size_t)(wv * 32 + 0 * 16 + lhi * 4 + q) * NV + sn0 + l15] = s0[q] + bv;
      out[(size_t)(wv * 32 + 1 * 16 + lhi * 4 + q) * NV + sn0 + l15] = s1[q] + bv;
    }
  }
}

extern "C" void kernel_launch(void* const* d_in, const int* in_sizes, int n_in,
                              void* d_out, int out_size, void* d_ws, size_t ws_size,
                              hipStream_t stream) {
  const int*   dec    = (const int*)d_in[0];
  const float* hidden = (const float*)d_in[1];
  const float* cell   = (const float*)d_in[2];
  const float* enc    = (const float*)d_in[3];
  const float* emb    = (const float*)d_in[4];
  const float* attn_w = (const float*)d_in[5];
  // d_in[6] = attn_b (cancels in softmax)
  const float* w_ih0  = (const float*)d_in[7];
  const float* w_hh0  = (const float*)d_in[8];
  const float* b_ih0  = (const float*)d_in[9];
  const float* b_hh0  = (const float*)d_in[10];
  const float* w_ih1  = (const float*)d_in[11];
  const float* w_hh1  = (const float*)d_in[12];
  const float* b_ih1  = (const float*)d_in[13];
  const float* b_hh1  = (const float*)d_in[14];
  const float* fc_w   = (const float*)d_in[15];
  const float* fc_b   = (const float*)d_in[16];
  float* out = (float*)d_out;
  float* ws  = (float*)d_ws;

  float* pctx = ws + OFF_PCTX;
  float* pml  = ws + OFF_PML;
  __hip_bfloat16* xbf   = (__hip_bfloat16*)(ws + OFF_XBF);
  __hip_bfloat16* h0nbf = (__hip_bfloat16*)(ws + OFF_H0NBF);
  __hip_bfloat16* h1nbf = (__hip_bfloat16*)(ws + OFF_H1NBF);
  __hip_bfloat16* h0bf  = (__hip_bfloat16*)(ws + OFF_H0BFI);
  __hip_bfloat16* h1bf  = (__hip_bfloat16*)(ws + OFF_H1BFI);

  attn_partial_k<<<dim3(NSC, NB), 256, 0, stream>>>(enc, attn_w, pctx, pml);
  attn_finish_k<<<NB, 256, 0, stream>>>(pctx, pml, emb, dec, hidden,
                                        xbf, h0bf, h1bf);
  lstm_fused_k<<<NH / 4, 256, 0, stream>>>(w_ih0, NX, w_hh0, xbf, h0bf,
                                           b_ih0, b_hh0, cell,
                                           out + OUT_HID, out + OUT_CELL, h0nbf);
  lstm_fused_k<<<NH / 4, 256, 0, stream>>>(w_ih1, NH, w_hh1, h0nbf, h1bf,
                                           b_ih1, b_hh1, cell + NB * NH,
                                           out + OUT_HID + (size_t)NB * NH,
                                           out + OUT_CELL + (size_t)NB * NH, h1nbf);
  gemm_fc_pipe_k<<<FC_BLOCKS, 256, 0, stream>>>(h1nbf, fc_w, fc_b, out);
}